// Round 16
// baseline (119.229 us; speedup 1.0000x reference)
//
#include <hip/hip_runtime.h>

#define N_NODES 50000
#define N_EDGES 600000
#define DIM 128
#define ZERO_BLOCKS ((N_NODES + 255) / 256)   // 196
#define GEMM_TILES ((N_NODES + 63) / 64)      // 782
#define HIST_BLOCKS ((N_EDGES + 255) / 256)   // 2344
#define SCAN_BLOCKS ((N_NODES + 255) / 256)   // 196

typedef __attribute__((ext_vector_type(8))) short short8;
typedef __attribute__((ext_vector_type(4))) float f32x4;

__device__ __forceinline__ unsigned bf16rne(float f) {
  unsigned x = __float_as_uint(f);
  x += 0x7fffu + ((x >> 16) & 1u);
  return x >> 16;
}

__device__ __forceinline__ short8 cvt8(float4 a, float4 b) {
  short8 r;
  r[0] = (short)bf16rne(a.x); r[1] = (short)bf16rne(a.y);
  r[2] = (short)bf16rne(a.z); r[3] = (short)bf16rne(a.w);
  r[4] = (short)bf16rne(b.x); r[5] = (short)bf16rne(b.y);
  r[6] = (short)bf16rne(b.z); r[7] = (short)bf16rne(b.w);
  return r;
}

__device__ __forceinline__ void fma8(float* a, uint4 v, float w) {
  a[0] += __uint_as_float(v.x << 16) * w;
  a[1] += __uint_as_float(v.x & 0xffff0000u) * w;
  a[2] += __uint_as_float(v.y << 16) * w;
  a[3] += __uint_as_float(v.y & 0xffff0000u) * w;
  a[4] += __uint_as_float(v.z << 16) * w;
  a[5] += __uint_as_float(v.z & 0xffff0000u) * w;
  a[6] += __uint_as_float(v.w << 16) * w;
  a[7] += __uint_as_float(v.w & 0xffff0000u) * w;
}

// ---------------------------------------------------------------------------
// K1: heterogeneous. Blocks [0, ZERO_BLOCKS): deg = 0, gtotal = 0.
// Blocks [ZERO_BLOCKS, +GEMM_TILES): MFMA tile with INLINE f32->bf16 cvt
// of nf and W fragments (no nf16/wt intermediates; nf read exactly once),
// transposed-C (r14), then LDS-staged epilogue: quadrants -> 32KB swizzled
// LDS tile -> cooperative full-256B-row stores (fixes r14's 48.8MB vs
// 25.6MB sub-line write amplification).
//   Y1 = nf @ W[:, :128]^T        (bf16, for the gather)
//   Y2 = nf @ W[:, 128:]^T + b    (bf16)
// ---------------------------------------------------------------------------
__global__ __launch_bounds__(256) void k_zero_gemm(
    const float* __restrict__ nf, const float* __restrict__ W,
    const float* __restrict__ bias,
    int* __restrict__ deg, int* __restrict__ gtotal,
    unsigned short* __restrict__ y1, unsigned short* __restrict__ y2) {
  __shared__ char yl[32768];          // [2 halves][64 rows][32 x 8B granules]
  if (blockIdx.x < ZERO_BLOCKS) {
    int i = blockIdx.x * 256 + threadIdx.x;
    if (i == 0) *gtotal = 0;
    if (i < N_NODES) deg[i] = 0;
    return;
  }
  const int tile = blockIdx.x - ZERO_BLOCKS;
  const int node0 = tile * 64;
  const int tid = threadIdx.x;
  const int lane = tid & 63;
  const int wv = tid >> 6;
  const int l16 = lane & 15, lg = lane >> 4;

  f32x4 acc[4][4] = {};   // [m: node frag][n: j frag]
#pragma unroll
  for (int ks = 0; ks < 4; ++ks) {           // K = 128 = 4 x 32
    short8 anf[4], awt[4];
#pragma unroll
    for (int m = 0; m < 4; ++m) {
      int node = node0 + m * 16 + l16;
      if (node > N_NODES - 1) node = N_NODES - 1;   // tail: masked at store
      const float4* p = reinterpret_cast<const float4*>(
          nf + (size_t)node * DIM + ks * 32 + lg * 8);
      anf[m] = cvt8(p[0], p[1]);
    }
#pragma unroll
    for (int n = 0; n < 4; ++n) {
      int j = wv * 64 + n * 16 + l16;
      int wr = (j < 128) ? j : (j - 128);
      int wc = ((j < 128) ? 0 : 128) + ks * 32 + lg * 8;
      const float4* q = reinterpret_cast<const float4*>(W + (size_t)wr * 256 + wc);
      awt[n] = cvt8(q[0], q[1]);
    }
#pragma unroll
    for (int m = 0; m < 4; ++m)
#pragma unroll
      for (int n = 0; n < 4; ++n)
        acc[m][n] = __builtin_amdgcn_mfma_f32_16x16x32_bf16(awt[n], anf[m], acc[m][n], 0, 0, 0);
  }

  // ---- epilogue 1: quadrants -> swizzled LDS (uint2 per fragment row) ----
  const int half = wv >> 1;                  // 0 -> Y1, 1 -> Y2
  const int j64 = (wv & 1) * 64;
#pragma unroll
  for (int n = 0; n < 4; ++n) {
    int jb = j64 + n * 16 + lg * 4;          // j within the 128-half
    float4 bv = make_float4(0.f, 0.f, 0.f, 0.f);
    if (half) bv = *reinterpret_cast<const float4*>(bias + jb);
    int g8 = jb >> 2;                        // 8B granule index (0..31)
#pragma unroll
    for (int m = 0; m < 4; ++m) {
      int node = m * 16 + l16;
      uint2 st;
      st.x = bf16rne(acc[m][n][0] + bv.x) | (bf16rne(acc[m][n][1] + bv.y) << 16);
      st.y = bf16rne(acc[m][n][2] + bv.z) | (bf16rne(acc[m][n][3] + bv.w) << 16);
      *reinterpret_cast<uint2*>(
          yl + half * 16384 + node * 256 + ((g8 ^ (node & 7)) * 8)) = st;
    }
  }
  __syncthreads();

  // ---- epilogue 2: cooperative full-row write-out (128B per thread) ----
  const int h2 = tid >> 7;                   // 0 -> y1, 1 -> y2
  const int idx = tid & 127;
  const int r = idx >> 1;                    // local row 0..63
  const int seg = idx & 1;                   // 128B segment of the 256B row
  int gnode = node0 + r;
  if (gnode < N_NODES) {
    uint2 tmp[16];
#pragma unroll
    for (int i = 0; i < 16; ++i) {
      int g8 = seg * 16 + i;
      tmp[i] = *reinterpret_cast<const uint2*>(
          yl + h2 * 16384 + r * 256 + ((g8 ^ (r & 7)) * 8));
    }
    unsigned short* yb = h2 ? y2 : y1;
    uint4* d4 = reinterpret_cast<uint4*>(yb + (size_t)gnode * 128 + seg * 64);
#pragma unroll
    for (int i = 0; i < 8; ++i)
      d4[i] = make_uint4(tmp[2 * i].x, tmp[2 * i].y, tmp[2 * i + 1].x, tmp[2 * i + 1].y);
  }
}

// ---------------------------------------------------------------------------
// K2: rank[e] = deg[dst[e]]++   (atomic return -> coalesced store)
// ---------------------------------------------------------------------------
__global__ __launch_bounds__(256) void k_hist(
    const int* __restrict__ dst, int* __restrict__ deg, int* __restrict__ rank) {
  int e = blockIdx.x * 256 + threadIdx.x;
  if (e < N_EDGES) rank[e] = atomicAdd(&deg[dst[e]], 1);
}

// ---------------------------------------------------------------------------
// K3: fused exclusive scan of deg -> cursor; block base via atomicAdd
// ---------------------------------------------------------------------------
__global__ __launch_bounds__(256) void k_scan(
    const int* __restrict__ deg, int* __restrict__ cursor,
    int* __restrict__ gtotal) {
  __shared__ int s[256];
  __shared__ int base;
  int t = threadIdx.x;
  int i = blockIdx.x * 256 + t;
  int v = (i < N_NODES) ? deg[i] : 0;
  s[t] = v;
  __syncthreads();
#pragma unroll
  for (int d = 1; d < 256; d <<= 1) {
    int add = (t >= d) ? s[t - d] : 0;
    __syncthreads();
    s[t] += add;
    __syncthreads();
  }
  int incl = s[t];
  if (t == 255) base = atomicAdd(gtotal, incl);
  __syncthreads();
  if (i < N_NODES) cursor[i] = base + incl - v;
}

// ---------------------------------------------------------------------------
// K4: srcw[cursor[dst[e]] + rank[e]] = src | (u16(w*65535) << 16)  (no atomics)
// ---------------------------------------------------------------------------
__global__ __launch_bounds__(256) void k_scatter(
    const int* __restrict__ src, const int* __restrict__ dst,
    const float* __restrict__ ew, const int* __restrict__ cursor,
    const int* __restrict__ rank, unsigned* __restrict__ srcw) {
  int e = blockIdx.x * 256 + threadIdx.x;
  if (e >= N_EDGES) return;
  int pos = cursor[dst[e]] + rank[e];
  unsigned wq = (unsigned)rintf(ew[e] * 65535.0f);
  srcw[pos] = (unsigned)src[e] | (wq << 16);
}

// ---------------------------------------------------------------------------
// K5: gather-final (r6-proven 8x8 structure over sequential CSR bucket).
// out[n] = (sum_e w_e * Y1[src_e]) / max(deg,1) + Y2[n]   (f32 write)
// ---------------------------------------------------------------------------
__global__ __launch_bounds__(256) void k_gather(
    const uint4* __restrict__ y1q,   // [N][16] granules of 8 bf16
    const uint4* __restrict__ y2q,
    const int* __restrict__ cursor, const int* __restrict__ deg,
    const unsigned* __restrict__ srcw, float4* __restrict__ out4) {
  int node = blockIdx.x * 4 + (threadIdx.x >> 6);
  int lane = threadIdx.x & 63;
  int g = lane >> 3;          // edge group 0..7
  int c = lane & 7;           // 32B chunk 0..7
  int dg = deg[node];
  int off = cursor[node];

  float a[16];
#pragma unroll
  for (int k = 0; k < 16; ++k) a[k] = 0.f;

  for (int j = g; j < dg; j += 8) {
    unsigned q = srcw[off + j];
    float w = (float)(q >> 16) * (1.0f / 65535.0f);
    const uint4* rp = y1q + (size_t)(q & 0xffffu) * 16 + c * 2;
    uint4 v0 = rp[0];
    uint4 v1 = rp[1];
    fma8(a, v0, w);
    fma8(a + 8, v1, w);
  }
#pragma unroll
  for (int k = 0; k < 16; ++k) {
    a[k] += __shfl_xor(a[k], 8);
    a[k] += __shfl_xor(a[k], 16);
    a[k] += __shfl_xor(a[k], 32);
  }
  if (g == 0) {
    float inv = 1.0f / (float)max(dg, 1);
    uint4 u0 = y2q[(size_t)node * 16 + c * 2];
    uint4 u1 = y2q[(size_t)node * 16 + c * 2 + 1];
    float4 o0, o1, o2, o3;
    o0.x = a[0] * inv + __uint_as_float(u0.x << 16);
    o0.y = a[1] * inv + __uint_as_float(u0.x & 0xffff0000u);
    o0.z = a[2] * inv + __uint_as_float(u0.y << 16);
    o0.w = a[3] * inv + __uint_as_float(u0.y & 0xffff0000u);
    o1.x = a[4] * inv + __uint_as_float(u0.z << 16);
    o1.y = a[5] * inv + __uint_as_float(u0.z & 0xffff0000u);
    o1.z = a[6] * inv + __uint_as_float(u0.w << 16);
    o1.w = a[7] * inv + __uint_as_float(u0.w & 0xffff0000u);
    o2.x = a[8] * inv + __uint_as_float(u1.x << 16);
    o2.y = a[9] * inv + __uint_as_float(u1.x & 0xffff0000u);
    o2.z = a[10] * inv + __uint_as_float(u1.y << 16);
    o2.w = a[11] * inv + __uint_as_float(u1.y & 0xffff0000u);
    o3.x = a[12] * inv + __uint_as_float(u1.z << 16);
    o3.y = a[13] * inv + __uint_as_float(u1.z & 0xffff0000u);
    o3.z = a[14] * inv + __uint_as_float(u1.w << 16);
    o3.w = a[15] * inv + __uint_as_float(u1.w & 0xffff0000u);
    float4* op = out4 + (size_t)node * 32 + c * 4;
    op[0] = o0; op[1] = o1; op[2] = o2; op[3] = o3;
  }
}

extern "C" void kernel_launch(void* const* d_in, const int* in_sizes, int n_in,
                              void* d_out, int out_size, void* d_ws, size_t ws_size,
                              hipStream_t stream) {
  const float* nf  = (const float*)d_in[0];  // [N, 128]
  const float* ew  = (const float*)d_in[1];  // [E, 1]
  const float* W   = (const float*)d_in[2];  // [128, 256]
  const float* b   = (const float*)d_in[3];  // [128]
  const int*   src = (const int*)d_in[4];    // [E]
  const int*   dst = (const int*)d_in[5];    // [E]
  float* out = (float*)d_out;                // [N, 128] f32

  // workspace layout (~30.8 MB of ~256 MiB ws), 16B-aligned offsets
  char* ws = (char*)d_ws;
  char* y1 = ws;                                       // 12,800,000
  char* y2 = y1 + (size_t)N_NODES * DIM * 2;           // 12,800,000
  int*  deg    = (int*)(y2 + (size_t)N_NODES * DIM * 2); // 200,000
  int*  cursor = deg + N_NODES;                        // 200,000
  int*  gtotal = cursor + N_NODES;                     // 4 (+pad to 1KB)
  int*  rank   = gtotal + 256;                         // 2,400,000
  unsigned* srcw = (unsigned*)(rank + N_EDGES);        // 2,400,000

  k_zero_gemm<<<ZERO_BLOCKS + GEMM_TILES, 256, 0, stream>>>(
      nf, W, b, deg, gtotal, (unsigned short*)y1, (unsigned short*)y2);
  k_hist<<<HIST_BLOCKS, 256, 0, stream>>>(dst, deg, rank);
  k_scan<<<SCAN_BLOCKS, 256, 0, stream>>>(deg, cursor, gtotal);
  k_scatter<<<(N_EDGES + 255) / 256, 256, 0, stream>>>(
      src, dst, ew, cursor, rank, srcw);
  k_gather<<<N_NODES / 4, 256, 0, stream>>>(
      (const uint4*)y1, (const uint4*)y2, cursor, deg, srcw, (float4*)out);
}

// Round 17
// 101.583 us; speedup vs baseline: 1.1737x; 1.1737x over previous
//
#include <hip/hip_runtime.h>

#define N_NODES 50000
#define N_EDGES 600000
#define DIM 128
#define NF4N (N_NODES * DIM / 4)              // 1,600,000
#define WTN (256 * 128)                       // 32,768
#define HIST_BLOCKS ((N_EDGES + 255) / 256)   // 2344
#define GEMM_TILES ((N_NODES + 63) / 64)      // 782
#define SCAN_BLOCKS ((N_NODES + 255) / 256)   // 196

typedef __attribute__((ext_vector_type(8))) short short8;
typedef __attribute__((ext_vector_type(4))) float f32x4;

__device__ __forceinline__ unsigned bf16rne(float f) {
  unsigned x = __float_as_uint(f);
  x += 0x7fffu + ((x >> 16) & 1u);
  return x >> 16;
}

__device__ __forceinline__ uint2 pack4(float4 v) {
  uint2 o;
  o.x = bf16rne(v.x) | (bf16rne(v.y) << 16);
  o.y = bf16rne(v.z) | (bf16rne(v.w) << 16);
  return o;
}

__device__ __forceinline__ void fma8(float* a, uint4 v, float w) {
  a[0] += __uint_as_float(v.x << 16) * w;
  a[1] += __uint_as_float(v.x & 0xffff0000u) * w;
  a[2] += __uint_as_float(v.y << 16) * w;
  a[3] += __uint_as_float(v.y & 0xffff0000u) * w;
  a[4] += __uint_as_float(v.z << 16) * w;
  a[5] += __uint_as_float(v.z & 0xffff0000u) * w;
  a[6] += __uint_as_float(v.w << 16) * w;
  a[7] += __uint_as_float(v.w & 0xffff0000u) * w;
}

// ---------------------------------------------------------------------------
// K1: deg = 0, gtotal = 0, W -> Wt bf16 remap, nf -> bf16 (r14-proven).
// Wt[j][k]: j<128 -> W[j][k] (agg-half); j>=128 -> W[j-128][128+k] (self-half)
// ---------------------------------------------------------------------------
__global__ __launch_bounds__(256) void k_init(
    const float4* __restrict__ nf4, uint2* __restrict__ nf16d,
    const float* __restrict__ Wf, unsigned short* __restrict__ wt,
    int* __restrict__ deg, int* __restrict__ gtotal) {
  int i = blockIdx.x * 256 + threadIdx.x;
  if (i == 0) *gtotal = 0;
  if (i < N_NODES) deg[i] = 0;
  if (i < WTN) {
    int j = i >> 7, k = i & 127;
    float v = (j < 128) ? Wf[j * 256 + k] : Wf[(j - 128) * 256 + 128 + k];
    wt[i] = (unsigned short)bf16rne(v);
  }
  if (i < NF4N) nf16d[i] = pack4(nf4[i]);
}

// ---------------------------------------------------------------------------
// K2: heterogeneous (r14-proven overlap). Blocks [0, HIST_BLOCKS):
// rank[e] = deg[dst[e]]++. Blocks [HIST_BLOCKS, +GEMM_TILES): MFMA tile.
// r16 post-mortem: the gemm is bound by per-lane SCATTERED 16B fragment
// loads (each lane a different row). Fix: stage the 16KB A-tile into LDS
// with 4 COALESCED uint4 loads/thread (XOR-swizzled granules, g^=(r&7);
// 16-lane fragment reads then span all 32 banks, 2-way = free). A-frags
// from LDS; only W's 16 short8 loads stay global (L2-hot).
// Transposed-C epilogue, packed 8B stores (r14).
// ---------------------------------------------------------------------------
__global__ __launch_bounds__(256) void k_hist_gemm(
    const int* __restrict__ dst, int* __restrict__ deg, int* __restrict__ rank,
    const char* __restrict__ nf16, const char* __restrict__ wt,
    const float* __restrict__ bias,
    unsigned short* __restrict__ y1, unsigned short* __restrict__ y2) {
  __shared__ char As[16384];          // 64 rows x 16 granules(16B), swizzled
  if (blockIdx.x < HIST_BLOCKS) {
    int e = blockIdx.x * 256 + threadIdx.x;
    if (e < N_EDGES) rank[e] = atomicAdd(&deg[dst[e]], 1);
    return;
  }
  const int tile = blockIdx.x - HIST_BLOCKS;
  const int node0 = tile * 64;
  const int tid = threadIdx.x;

  // ---- stage A tile: 1024 granules, 4 coalesced uint4 loads/thread ----
#pragma unroll
  for (int i = 0; i < 4; ++i) {
    int G = tid + i * 256;
    int r = G >> 4, g = G & 15;
    int node = node0 + r;
    if (node > N_NODES - 1) node = N_NODES - 1;   // tail: masked at store
    uint4 v = *reinterpret_cast<const uint4*>(nf16 + (size_t)node * 256 + g * 16);
    *reinterpret_cast<uint4*>(As + r * 256 + ((g ^ (r & 7)) * 16)) = v;
  }
  __syncthreads();

  const int lane = tid & 63;
  const int wv = tid >> 6;
  const int l16 = lane & 15, lg = lane >> 4;

  f32x4 acc[4][4] = {};   // [m: node frag][n: j frag]
#pragma unroll
  for (int ks = 0; ks < 4; ++ks) {           // K = 128 = 4 x 32
    short8 anf[4], awt[4];
#pragma unroll
    for (int m = 0; m < 4; ++m) {
      int r = m * 16 + l16;
      int g = ks * 4 + lg;
      anf[m] = *reinterpret_cast<const short8*>(As + r * 256 + ((g ^ (r & 7)) * 16));
    }
#pragma unroll
    for (int n = 0; n < 4; ++n) {
      int j = wv * 64 + n * 16 + l16;
      awt[n] = *reinterpret_cast<const short8*>(wt + (size_t)j * 256 + ks * 64 + lg * 16);
    }
#pragma unroll
    for (int m = 0; m < 4; ++m)
#pragma unroll
      for (int n = 0; n < 4; ++n)
        acc[m][n] = __builtin_amdgcn_mfma_f32_16x16x32_bf16(awt[n], anf[m], acc[m][n], 0, 0, 0);
  }

  // epilogue: per (m,n) one packed 8B store of 4 consecutive j (r14)
  const bool isY2 = (wv >= 2);
  unsigned short* yb = isY2 ? y2 : y1;
  const int jhalf = (wv & 1) * 64;
#pragma unroll
  for (int n = 0; n < 4; ++n) {
    int jb = jhalf + n * 16 + lg * 4;
    float4 bv = make_float4(0.f, 0.f, 0.f, 0.f);
    if (isY2) bv = *reinterpret_cast<const float4*>(bias + jb);
#pragma unroll
    for (int m = 0; m < 4; ++m) {
      int node = node0 + m * 16 + l16;
      if (node >= N_NODES) continue;
      uint2 st;
      st.x = bf16rne(acc[m][n][0] + bv.x) | (bf16rne(acc[m][n][1] + bv.y) << 16);
      st.y = bf16rne(acc[m][n][2] + bv.z) | (bf16rne(acc[m][n][3] + bv.w) << 16);
      *reinterpret_cast<uint2*>(yb + (size_t)node * 128 + jb) = st;
    }
  }
}

// ---------------------------------------------------------------------------
// K3: fused exclusive scan of deg -> cursor; block base via atomicAdd
// ---------------------------------------------------------------------------
__global__ __launch_bounds__(256) void k_scan(
    const int* __restrict__ deg, int* __restrict__ cursor,
    int* __restrict__ gtotal) {
  __shared__ int s[256];
  __shared__ int base;
  int t = threadIdx.x;
  int i = blockIdx.x * 256 + t;
  int v = (i < N_NODES) ? deg[i] : 0;
  s[t] = v;
  __syncthreads();
#pragma unroll
  for (int d = 1; d < 256; d <<= 1) {
    int add = (t >= d) ? s[t - d] : 0;
    __syncthreads();
    s[t] += add;
    __syncthreads();
  }
  int incl = s[t];
  if (t == 255) base = atomicAdd(gtotal, incl);
  __syncthreads();
  if (i < N_NODES) cursor[i] = base + incl - v;
}

// ---------------------------------------------------------------------------
// K4: srcw[cursor[dst[e]] + rank[e]] = src | (u16(w*65535) << 16)  (no atomics)
// ---------------------------------------------------------------------------
__global__ __launch_bounds__(256) void k_scatter(
    const int* __restrict__ src, const int* __restrict__ dst,
    const float* __restrict__ ew, const int* __restrict__ cursor,
    const int* __restrict__ rank, unsigned* __restrict__ srcw) {
  int e = blockIdx.x * 256 + threadIdx.x;
  if (e >= N_EDGES) return;
  int pos = cursor[dst[e]] + rank[e];
  unsigned wq = (unsigned)rintf(ew[e] * 65535.0f);
  srcw[pos] = (unsigned)src[e] | (wq << 16);
}

// ---------------------------------------------------------------------------
// K5: gather-final (r6-proven 8x8 structure over sequential CSR bucket).
// out[n] = (sum_e w_e * Y1[src_e]) / max(deg,1) + Y2[n]   (f32 write)
// ---------------------------------------------------------------------------
__global__ __launch_bounds__(256) void k_gather(
    const uint4* __restrict__ y1q,   // [N][16] granules of 8 bf16
    const uint4* __restrict__ y2q,
    const int* __restrict__ cursor, const int* __restrict__ deg,
    const unsigned* __restrict__ srcw, float4* __restrict__ out4) {
  int node = blockIdx.x * 4 + (threadIdx.x >> 6);
  int lane = threadIdx.x & 63;
  int g = lane >> 3;          // edge group 0..7
  int c = lane & 7;           // 32B chunk 0..7
  int dg = deg[node];
  int off = cursor[node];

  float a[16];
#pragma unroll
  for (int k = 0; k < 16; ++k) a[k] = 0.f;

  for (int j = g; j < dg; j += 8) {
    unsigned q = srcw[off + j];
    float w = (float)(q >> 16) * (1.0f / 65535.0f);
    const uint4* rp = y1q + (size_t)(q & 0xffffu) * 16 + c * 2;
    uint4 v0 = rp[0];
    uint4 v1 = rp[1];
    fma8(a, v0, w);
    fma8(a + 8, v1, w);
  }
#pragma unroll
  for (int k = 0; k < 16; ++k) {
    a[k] += __shfl_xor(a[k], 8);
    a[k] += __shfl_xor(a[k], 16);
    a[k] += __shfl_xor(a[k], 32);
  }
  if (g == 0) {
    float inv = 1.0f / (float)max(dg, 1);
    uint4 u0 = y2q[(size_t)node * 16 + c * 2];
    uint4 u1 = y2q[(size_t)node * 16 + c * 2 + 1];
    float4 o0, o1, o2, o3;
    o0.x = a[0] * inv + __uint_as_float(u0.x << 16);
    o0.y = a[1] * inv + __uint_as_float(u0.x & 0xffff0000u);
    o0.z = a[2] * inv + __uint_as_float(u0.y << 16);
    o0.w = a[3] * inv + __uint_as_float(u0.y & 0xffff0000u);
    o1.x = a[4] * inv + __uint_as_float(u0.z << 16);
    o1.y = a[5] * inv + __uint_as_float(u0.z & 0xffff0000u);
    o1.z = a[6] * inv + __uint_as_float(u0.w << 16);
    o1.w = a[7] * inv + __uint_as_float(u0.w & 0xffff0000u);
    o2.x = a[8] * inv + __uint_as_float(u1.x << 16);
    o2.y = a[9] * inv + __uint_as_float(u1.x & 0xffff0000u);
    o2.z = a[10] * inv + __uint_as_float(u1.y << 16);
    o2.w = a[11] * inv + __uint_as_float(u1.y & 0xffff0000u);
    o3.x = a[12] * inv + __uint_as_float(u1.z << 16);
    o3.y = a[13] * inv + __uint_as_float(u1.z & 0xffff0000u);
    o3.z = a[14] * inv + __uint_as_float(u1.w << 16);
    o3.w = a[15] * inv + __uint_as_float(u1.w & 0xffff0000u);
    float4* op = out4 + (size_t)node * 32 + c * 4;
    op[0] = o0; op[1] = o1; op[2] = o2; op[3] = o3;
  }
}

extern "C" void kernel_launch(void* const* d_in, const int* in_sizes, int n_in,
                              void* d_out, int out_size, void* d_ws, size_t ws_size,
                              hipStream_t stream) {
  const float* nf  = (const float*)d_in[0];  // [N, 128]
  const float* ew  = (const float*)d_in[1];  // [E, 1]
  const float* W   = (const float*)d_in[2];  // [128, 256]
  const float* b   = (const float*)d_in[3];  // [128]
  const int*   src = (const int*)d_in[4];    // [E]
  const int*   dst = (const int*)d_in[5];    // [E]
  float* out = (float*)d_out;                // [N, 128] f32

  // workspace layout (~43.7 MB of ~256 MiB ws), 16B-aligned offsets
  char* ws = (char*)d_ws;
  char* nf16 = ws;                                     // 12,800,000
  char* wt   = nf16 + (size_t)N_NODES * DIM * 2;       // 65,536
  char* y1   = wt + (size_t)WTN * 2;                   // 12,800,000
  char* y2   = y1 + (size_t)N_NODES * DIM * 2;         // 12,800,000
  int*  deg    = (int*)(y2 + (size_t)N_NODES * DIM * 2); // 200,000
  int*  cursor = deg + N_NODES;                        // 200,000
  int*  gtotal = cursor + N_NODES;                     // 4 (+pad to 1KB)
  int*  rank   = gtotal + 256;                         // 2,400,000
  unsigned* srcw = (unsigned*)(rank + N_EDGES);        // 2,400,000

  k_init<<<NF4N / 256, 256, 0, stream>>>(
      (const float4*)nf, (uint2*)nf16, W, (unsigned short*)wt, deg, gtotal);
  k_hist_gemm<<<HIST_BLOCKS + GEMM_TILES, 256, 0, stream>>>(
      dst, deg, rank, nf16, wt, b, (unsigned short*)y1, (unsigned short*)y2);
  k_scan<<<SCAN_BLOCKS, 256, 0, stream>>>(deg, cursor, gtotal);
  k_scatter<<<(N_EDGES + 255) / 256, 256, 0, stream>>>(
      src, dst, ew, cursor, rank, srcw);
  k_gather<<<N_NODES / 4, 256, 0, stream>>>(
      (const uint4*)y1, (const uint4*)y2, cursor, deg, srcw, (float4*)out);
}